// Round 9
// baseline (249.898 us; speedup 1.0000x reference)
//
#include <hip/hip_runtime.h>
#include <hip/hip_cooperative_groups.h>

namespace cg = cooperative_groups;

#define BB 32
#define MM 512
#define SS 10
#define VV 32000
#define DD 128
#define HOPS 3
#define BM (BB * MM)
#define NCHUNK 32          // chunks per b -> 32*32 = 1024 hop items
#define NITEM (BB * NCHUNK)
#define CHM (MM / NCHUNK)  // 16 m per chunk -> 4 m per wave
#define PSTRIDE 132        // partial row: 128 num + 1 den + pad
#define GTHR 256
#define UTAB ((size_t)VV * DD / 8)   // cvt units (8 f32) per table = 512000

// bf16 helpers (RN pack; exact unpack)
__device__ __forceinline__ unsigned bfrn(float f) {
    unsigned u = __float_as_uint(f);
    return (u + 0x7FFFu + ((u >> 16) & 1u)) >> 16;
}
__device__ __forceinline__ float bflo(unsigned q) { return __uint_as_float(q << 16); }
__device__ __forceinline__ float bfhi(unsigned q) { return __uint_as_float(q & 0xFFFF0000u); }

__device__ __forceinline__ void cvt_unit(const float* __restrict__ C,
                                         unsigned* __restrict__ Cb, size_t gid) {
    const float4 f0 = ((const float4*)C)[gid * 2];
    const float4 f1 = ((const float4*)C)[gid * 2 + 1];
    uint4 o;
    o.x = bfrn(f0.x) | (bfrn(f0.y) << 16);
    o.y = bfrn(f0.z) | (bfrn(f0.w) << 16);
    o.z = bfrn(f1.x) | (bfrn(f1.y) << 16);
    o.w = bfrn(f1.z) | (bfrn(f1.w) << 16);
    ((uint4*)Cb)[gid] = o;
}

// One hop chunk (b,c). Max-free softmax partials: P row = [num[128] | den].
template <int HOP>
__device__ void hop_body(const int b, const int c, const int tid,
                         const int* __restrict__ story,
                         const unsigned* __restrict__ Clog,
                         const unsigned* __restrict__ Cout,
                         const float* __restrict__ Elog,
                         float* __restrict__ Eout,
                         const float* __restrict__ uprev,
                         const float* __restrict__ pin,
                         float* __restrict__ uwrite,
                         float* __restrict__ logit,
                         float* __restrict__ pout,
                         float* __restrict__ su,
                         float (*sx)[64], float (*sy)[64], float* sd) {
    const int w = tid >> 6, lane = tid & 63;

    if (tid < DD) {
        float v = uprev[b * DD + tid];
        if (HOP > 0) {
            float num = 0.f, dsum = 0.f;
            for (int cc = 0; cc < NCHUNK; ++cc) {
                const float* p = pin + ((size_t)b * NCHUNK + cc) * PSTRIDE;
                num += p[tid];
                dsum += p[DD];
            }
            v += num / dsum;
            if (c == 0) uwrite[b * DD + tid] = v;
        }
        su[tid] = v;
    }
    __syncthreads();
    const float2 uv = ((const float2*)su)[lane];

    float nx = 0.f, ny = 0.f, den = 0.f;
#pragma unroll
    for (int k = 0; k < CHM / 4; ++k) {
        const int m = c * CHM + k * 4 + w;
        const int bm = b * MM + m;
        int tok[SS];
        const int* st = story + (size_t)bm * SS;
#pragma unroll
        for (int s = 0; s < SS; ++s) tok[s] = st[s];

        float ex, ey;
        if (HOP == 0) {
            ex = 0.f; ey = 0.f;
#pragma unroll
            for (int s = 0; s < SS; ++s) {
                const unsigned q = (Clog + (size_t)tok[s] * (DD / 2))[lane];
                ex += bflo(q); ey += bfhi(q);
            }
        } else {
            const float2 v = ((const float2*)(Elog + (size_t)bm * DD))[lane];
            ex = v.x; ey = v.y;
        }
        float l = ex * uv.x + ey * uv.y;
#pragma unroll
        for (int off = 32; off; off >>= 1) l += __shfl_xor(l, off, 64);
        if (HOP == 2 && lane == 0) logit[bm] = l;
        const float e = expf(l);

        float rx = 0.f, ry = 0.f;
#pragma unroll
        for (int s = 0; s < SS; ++s) {
            const unsigned q = (Cout + (size_t)tok[s] * (DD / 2))[lane];
            rx += bflo(q); ry += bfhi(q);
        }
        if (HOP < 2)
            ((float2*)(Eout + (size_t)bm * DD))[lane] = make_float2(rx, ry);
        nx += e * rx; ny += e * ry; den += e;
    }

    __syncthreads();   // ensure prior-iteration LDS reads done before overwriting sx/sy
    sx[w][lane] = nx; sy[w][lane] = ny;
    if (lane == 0) sd[w] = den;
    __syncthreads();
    if (w == 0) {
        const float ox = sx[0][lane] + sx[1][lane] + sx[2][lane] + sx[3][lane];
        const float oy = sy[0][lane] + sy[1][lane] + sy[2][lane] + sy[3][lane];
        float* prow = pout + ((size_t)b * NCHUNK + c) * PSTRIDE;
        ((float2*)prow)[lane] = make_float2(ox, oy);
        if (lane == 0) prow[DD] = sd[0] + sd[1] + sd[2] + sd[3];
    }
}

// ====================== PRIMARY: one cooperative kernel (grid-stride) ======================
__global__ __launch_bounds__(GTHR, 2) void fused_all(const int* __restrict__ story,
                                                     const float* __restrict__ hidden,
                                                     const float* __restrict__ Cmat,
                                                     unsigned* __restrict__ Cb,
                                                     float* __restrict__ E1,
                                                     float* __restrict__ E2,
                                                     float* __restrict__ P0,
                                                     float* __restrict__ P1,
                                                     float* __restrict__ P2,
                                                     float* __restrict__ u1,
                                                     float* __restrict__ u2,
                                                     float* __restrict__ logit,
                                                     float* __restrict__ uout) {
    cg::grid_group grid = cg::this_grid();
    const int blk = blockIdx.x;
    const int tid = threadIdx.x;
    const int G = gridDim.x;
    const size_t GS = (size_t)G * GTHR;

    __shared__ float su[DD];
    __shared__ float sx[4][64], sy[4][64];
    __shared__ float sd[4];

    const unsigned* C0b = Cb;
    const unsigned* C1b = Cb + (size_t)1 * VV * DD / 2;
    const unsigned* C2b = Cb + (size_t)2 * VV * DD / 2;
    const unsigned* C3b = Cb + (size_t)3 * VV * DD / 2;

    // ---- phase 0: cvt tables 0,1 (needed by hop0) ----
    for (size_t g = (size_t)blk * GTHR + tid; g < 2 * UTAB; g += GS)
        cvt_unit(Cmat, Cb, g);
    grid.sync();

    // ---- phase 1: hop0 items, then share of cvt table 2 ----
    for (int item = blk; item < NITEM; item += G)
        hop_body<0>(item >> 5, item & 31, tid, story, C0b, C1b, nullptr, E1,
                    hidden, nullptr, nullptr, nullptr, P0, su, sx, sy, sd);
    for (size_t g = (size_t)blk * GTHR + tid; g < UTAB; g += GS)
        cvt_unit(Cmat, Cb, 2 * UTAB + g);
    grid.sync();

    // ---- phase 2: hop1 items, then share of cvt table 3 ----
    for (int item = blk; item < NITEM; item += G)
        hop_body<1>(item >> 5, item & 31, tid, story, nullptr, C2b, E1, E2,
                    hidden, P0, u1, nullptr, P1, su, sx, sy, sd);
    for (size_t g = (size_t)blk * GTHR + tid; g < UTAB; g += GS)
        cvt_unit(Cmat, Cb, 3 * UTAB + g);
    grid.sync();

    // ---- phase 3: hop2 items ----
    for (int item = blk; item < NITEM; item += G)
        hop_body<2>(item >> 5, item & 31, tid, story, nullptr, C3b, E2, nullptr,
                    u1, P1, u2, logit, P2, su, sx, sy, sd);
    grid.sync();

    // ---- phase 4: final u ----
    for (int item = blk; item < 16; item += G) {
        const int i = item * GTHR + tid;          // 0..4095
        const int bb = i >> 7, d = i & 127;
        float num = 0.f, dsum = 0.f;
        for (int cc = 0; cc < NCHUNK; ++cc) {
            const float* p = P2 + ((size_t)bb * NCHUNK + cc) * PSTRIDE;
            num += p[d];
            dsum += p[DD];
        }
        uout[bb * DD + d] = u2[bb * DD + d] + num / dsum;
    }
}

// ====================== SECONDARY: R7 5-kernel path (validated, 66 us) ======================
__global__ __launch_bounds__(256) void cvt_bf16(const float* __restrict__ C,
                                                unsigned* __restrict__ Cb) {
    const int gid = blockIdx.x * 256 + threadIdx.x;
    cvt_unit(C, Cb, (size_t)gid);
}

template <int HOP>
__global__ __launch_bounds__(256) void hop_k(const int* __restrict__ story,
                                             const unsigned* __restrict__ Clog,
                                             const unsigned* __restrict__ Cout,
                                             const float* __restrict__ Elog,
                                             float* __restrict__ Eout,
                                             const float* __restrict__ uprev,
                                             const float* __restrict__ pin,
                                             float* __restrict__ uwrite,
                                             float* __restrict__ logit,
                                             float* __restrict__ pout) {
    __shared__ float su[DD];
    __shared__ float sx[4][64], sy[4][64];
    __shared__ float sd[4];
    hop_body<HOP>(blockIdx.y, blockIdx.x, threadIdx.x, story, Clog, Cout, Elog,
                  Eout, uprev, pin, uwrite, logit, pout, su, sx, sy, sd);
}

__global__ __launch_bounds__(128) void final_u(const float* __restrict__ pin,
                                               const float* __restrict__ u2,
                                               float* __restrict__ uout) {
    const int b = blockIdx.x, d = threadIdx.x;
    float num = 0.f, den = 0.f;
    for (int cc = 0; cc < NCHUNK; ++cc) {
        const float* p = pin + ((size_t)b * NCHUNK + cc) * PSTRIDE;
        num += p[d];
        den += p[DD];
    }
    uout[b * DD + d] = u2[b * DD + d] + num / den;
}

// ====================== FALLBACK PATH (round-1, known-good) ======================
__global__ __launch_bounds__(256) void init_u(const float* __restrict__ hidden,
                                              float* __restrict__ u) {
    int i = blockIdx.x * 256 + threadIdx.x;
    if (i < BB * DD) u[i] = hidden[i];
}

__global__ __launch_bounds__(256) void logit_kernel(const int* __restrict__ story,
                                                    const float* __restrict__ Ch,
                                                    const float* __restrict__ u,
                                                    float* __restrict__ logit) {
    int wid = (blockIdx.x * 256 + threadIdx.x) >> 6;
    int lane = threadIdx.x & 63;
    if (wid >= BB * MM) return;
    int b = wid >> 9;
    const int* st = story + (size_t)wid * SS;
    int tok[SS];
#pragma unroll
    for (int s = 0; s < SS; ++s) tok[s] = st[s];
    float ax = 0.f, ay = 0.f;
#pragma unroll
    for (int s = 0; s < SS; ++s) {
        const float2 v = ((const float2*)(Ch + (size_t)tok[s] * DD))[lane];
        ax += v.x; ay += v.y;
    }
    const float2 uv = ((const float2*)(u + b * DD))[lane];
    float p = ax * uv.x + ay * uv.y;
#pragma unroll
    for (int off = 32; off; off >>= 1) p += __shfl_down(p, off, 64);
    if (lane == 0) logit[wid] = p;
}

__global__ __launch_bounds__(256) void softmax_kernel(const float* __restrict__ logit,
                                                      float* __restrict__ prob) {
    int b = blockIdx.x;
    int t = threadIdx.x;
    __shared__ float red[8];
    float l0 = logit[b * MM + t];
    float l1 = logit[b * MM + 256 + t];
    float mx = fmaxf(l0, l1);
#pragma unroll
    for (int off = 32; off; off >>= 1) mx = fmaxf(mx, __shfl_xor(mx, off, 64));
    if ((t & 63) == 0) red[t >> 6] = mx;
    __syncthreads();
    mx = fmaxf(fmaxf(red[0], red[1]), fmaxf(red[2], red[3]));
    float e0 = expf(l0 - mx), e1 = expf(l1 - mx);
    float s = e0 + e1;
#pragma unroll
    for (int off = 32; off; off >>= 1) s += __shfl_xor(s, off, 64);
    if ((t & 63) == 0) red[4 + (t >> 6)] = s;
    __syncthreads();
    s = red[4] + red[5] + red[6] + red[7];
    float inv = 1.0f / s;
    prob[b * MM + t] = e0 * inv;
    prob[b * MM + 256 + t] = e1 * inv;
}

__global__ __launch_bounds__(256) void partial_kernel(const int* __restrict__ story,
                                                      const float* __restrict__ Ch1,
                                                      const float* __restrict__ prob,
                                                      float* __restrict__ partial,
                                                      int chunk) {
    int b = blockIdx.y, c = blockIdx.x;
    int w = threadIdx.x >> 6, lane = threadIdx.x & 63;
    int m0 = c * chunk;
    float ax = 0.f, ay = 0.f;
    for (int m = m0 + w; m < m0 + chunk; m += 4) {
        float pw = prob[b * MM + m];
        const int* st = story + (size_t)(b * MM + m) * SS;
        int tok[SS];
#pragma unroll
        for (int s = 0; s < SS; ++s) tok[s] = st[s];
        float sx = 0.f, sy = 0.f;
#pragma unroll
        for (int s = 0; s < SS; ++s) {
            const float2 v = ((const float2*)(Ch1 + (size_t)tok[s] * DD))[lane];
            sx += v.x; sy += v.y;
        }
        ax += pw * sx; ay += pw * sy;
    }
    __shared__ float redx[4][64];
    __shared__ float redy[4][64];
    redx[w][lane] = ax;
    redy[w][lane] = ay;
    __syncthreads();
    if (w == 0) {
        float ox = redx[0][lane] + redx[1][lane] + redx[2][lane] + redx[3][lane];
        float oy = redy[0][lane] + redy[1][lane] + redy[2][lane] + redy[3][lane];
        float2* dst = (float2*)(partial + ((size_t)b * gridDim.x + c) * DD);
        dst[lane] = make_float2(ox, oy);
    }
}

__global__ __launch_bounds__(256) void update_kernel(const float* __restrict__ partial,
                                                     float* __restrict__ u, int NC) {
    int i = blockIdx.x * 256 + threadIdx.x;
    if (i >= BB * DD) return;
    int b = i >> 7, d = i & 127;
    float s = 0.f;
    for (int c = 0; c < NC; ++c) s += partial[((size_t)b * NC + c) * DD + d];
    u[i] += s;
}

extern "C" void kernel_launch(void* const* d_in, const int* in_sizes, int n_in,
                              void* d_out, int out_size, void* d_ws, size_t ws_size,
                              hipStream_t stream) {
    const int*   story  = (const int*)d_in[0];
    const float* hidden = (const float*)d_in[1];
    const float* Cmat   = (const float*)d_in[2];

    float* out   = (float*)d_out;
    float* logit = out;              // final prob_logit [B,M]
    float* uout  = out + BB * MM;    // final u [B,D]

    // ws layout (float words): Cb (bf16 pairs) | E1 | E2 | P0 P1 P2 | u1 u2
    const size_t szCb = (size_t)4 * VV * DD / 2;
    const size_t szE  = (size_t)BM * DD;
    const size_t szP  = (size_t)BB * NCHUNK * PSTRIDE;
    const size_t need = (szCb + 2 * szE + 3 * szP + 2 * BB * DD) * sizeof(float);

    if (ws_size >= need) {
        unsigned* Cb = (unsigned*)d_ws;
        float* E1 = (float*)d_ws + szCb;
        float* E2 = E1 + szE;
        float* P0 = E2 + szE;
        float* P1 = P0 + szP;
        float* P2 = P1 + szP;
        float* u1 = P2 + szP;
        float* u2 = u1 + BB * DD;

        const unsigned* C0b = Cb;
        const unsigned* C1b = Cb + (size_t)1 * VV * DD / 2;
        const unsigned* C2b = Cb + (size_t)2 * VV * DD / 2;
        const unsigned* C3b = Cb + (size_t)3 * VV * DD / 2;

        // ---- try cooperative fused path, sized by the occupancy API ----
        bool coop_done = false;
        int maxActive = 0;
        if (hipOccupancyMaxActiveBlocksPerMultiprocessor(&maxActive, fused_all,
                                                         GTHR, 0) == hipSuccess &&
            maxActive > 0) {
            hipDeviceProp_t prop;
            int dev = 0;
            hipGetDevice(&dev);
            if (hipGetDeviceProperties(&prop, dev) == hipSuccess) {
                int grid = maxActive * prop.multiProcessorCount;
                if (grid > NITEM) grid = NITEM;
                if (grid >= 256) {
                    void* args[] = {(void*)&story, (void*)&hidden, (void*)&Cmat,
                                    (void*)&Cb, (void*)&E1, (void*)&E2,
                                    (void*)&P0, (void*)&P1, (void*)&P2,
                                    (void*)&u1, (void*)&u2, (void*)&logit,
                                    (void*)&uout};
                    if (hipLaunchCooperativeKernel((void*)fused_all, dim3(grid),
                                                   dim3(GTHR), args, 0,
                                                   stream) == hipSuccess)
                        coop_done = true;
                }
            }
        }

        if (!coop_done) {
            // validated R7 multi-kernel path
            cvt_bf16<<<(4 * VV * DD / 8) / 256, 256, 0, stream>>>(Cmat, Cb);
            hop_k<0><<<dim3(NCHUNK, BB), 256, 0, stream>>>(
                story, C0b, C1b, nullptr, E1, hidden, nullptr, nullptr, nullptr, P0);
            hop_k<1><<<dim3(NCHUNK, BB), 256, 0, stream>>>(
                story, nullptr, C2b, E1, E2, hidden, P0, u1, nullptr, P1);
            hop_k<2><<<dim3(NCHUNK, BB), 256, 0, stream>>>(
                story, nullptr, C3b, E2, nullptr, u1, P1, u2, logit, P2);
            final_u<<<BB, 128, 0, stream>>>(P2, u2, uout);
        }
    } else {
        float* prob = (float*)d_ws;
        int NC = 32;
        while (NC > 1 && (size_t)(BB * MM + BB * NC * DD) * 4 > ws_size) NC >>= 1;
        float* partial = prob + BB * MM;
        int chunk = MM / NC;

        init_u<<<(BB * DD + 255) / 256, 256, 0, stream>>>(hidden, uout);
        for (int h = 0; h < HOPS; ++h) {
            const float* Ca = Cmat + (size_t)h * VV * DD;
            const float* Cc = Cmat + (size_t)(h + 1) * VV * DD;
            logit_kernel<<<(BB * MM) / 4, 256, 0, stream>>>(story, Ca, uout, logit);
            softmax_kernel<<<BB, 256, 0, stream>>>(logit, prob);
            partial_kernel<<<dim3(NC, BB), 256, 0, stream>>>(story, Cc, prob, partial, chunk);
            update_kernel<<<(BB * DD + 255) / 256, 256, 0, stream>>>(partial, uout, NC);
        }
    }
}

// Round 10
// 66.148 us; speedup vs baseline: 3.7778x; 3.7778x over previous
//
#include <hip/hip_runtime.h>

#define BB 32
#define MM 512
#define SS 10
#define VV 32000
#define DD 128
#define HOPS 3
#define BM (BB * MM)
#define NCHUNK 64          // chunks per b -> grid 64*32 = 2048 blocks per hop
#define CHM (MM / NCHUNK)  // 8 m per chunk -> 2 m per wave
#define PSTRIDE 132        // partial row: 128 num + 1 den + pad
#define UTAB ((size_t)VV * DD / 8)   // cvt units (8 f32) per table = 512000

// bf16 helpers (RN pack; exact unpack)
__device__ __forceinline__ unsigned bfrn(float f) {
    unsigned u = __float_as_uint(f);
    return (u + 0x7FFFu + ((u >> 16) & 1u)) >> 16;
}
__device__ __forceinline__ float bflo(unsigned q) { return __uint_as_float(q << 16); }
__device__ __forceinline__ float bfhi(unsigned q) { return __uint_as_float(q & 0xFFFF0000u); }

__device__ __forceinline__ void cvt_unit(const float* __restrict__ C,
                                         unsigned* __restrict__ Cb, size_t gid) {
    const float4 f0 = ((const float4*)C)[gid * 2];
    const float4 f1 = ((const float4*)C)[gid * 2 + 1];
    uint4 o;
    o.x = bfrn(f0.x) | (bfrn(f0.y) << 16);
    o.y = bfrn(f0.z) | (bfrn(f0.w) << 16);
    o.z = bfrn(f1.x) | (bfrn(f1.y) << 16);
    o.w = bfrn(f1.z) | (bfrn(f1.w) << 16);
    ((uint4*)Cb)[gid] = o;
}

// One hop chunk (b,c). Max-free softmax partials: P row = [num[128] | den].
// HOP0: logit gather Clog, out gather Cout (writes E1), uprev=hidden, no pin.
// HOP1: logit from Elog, out gather Cout (writes E2), u rebuilt from uprev+pin; c==0 -> uwrite.
// HOP2: logit from Elog (writes final logit), out gather Cout, u from uprev+pin; c==0 -> uwrite.
template <int HOP>
__device__ void hop_body(const int b, const int c, const int tid,
                         const int* __restrict__ story,
                         const unsigned* __restrict__ Clog,
                         const unsigned* __restrict__ Cout,
                         const float* __restrict__ Elog,
                         float* __restrict__ Eout,
                         const float* __restrict__ uprev,
                         const float* __restrict__ pin,
                         float* __restrict__ uwrite,
                         float* __restrict__ logit,
                         float* __restrict__ pout,
                         float* __restrict__ su,
                         float (*sx)[64], float (*sy)[64], float* sd) {
    const int w = tid >> 6, lane = tid & 63;

    if (tid < DD) {
        float v = uprev[b * DD + tid];
        if (HOP > 0) {
            float num = 0.f, dsum = 0.f;
            for (int cc = 0; cc < NCHUNK; ++cc) {
                const float* p = pin + ((size_t)b * NCHUNK + cc) * PSTRIDE;
                num += p[tid];
                dsum += p[DD];
            }
            v += num / dsum;
            if (c == 0) uwrite[b * DD + tid] = v;
        }
        su[tid] = v;
    }
    __syncthreads();
    const float2 uv = ((const float2*)su)[lane];

    float nx = 0.f, ny = 0.f, den = 0.f;
#pragma unroll
    for (int k = 0; k < CHM / 4; ++k) {
        const int m = c * CHM + k * 4 + w;
        const int bm = b * MM + m;
        int tok[SS];
        const int* st = story + (size_t)bm * SS;
#pragma unroll
        for (int s = 0; s < SS; ++s) tok[s] = st[s];

        float ex, ey;
        if (HOP == 0) {
            ex = 0.f; ey = 0.f;
#pragma unroll
            for (int s = 0; s < SS; ++s) {
                const unsigned q = (Clog + (size_t)tok[s] * (DD / 2))[lane];
                ex += bflo(q); ey += bfhi(q);
            }
        } else {
            const float2 v = ((const float2*)(Elog + (size_t)bm * DD))[lane];
            ex = v.x; ey = v.y;
        }
        float l = ex * uv.x + ey * uv.y;
#pragma unroll
        for (int off = 32; off; off >>= 1) l += __shfl_xor(l, off, 64);
        if (HOP == 2 && lane == 0) logit[bm] = l;
        const float e = expf(l);

        float rx = 0.f, ry = 0.f;
#pragma unroll
        for (int s = 0; s < SS; ++s) {
            const unsigned q = (Cout + (size_t)tok[s] * (DD / 2))[lane];
            rx += bflo(q); ry += bfhi(q);
        }
        if (HOP < 2)
            ((float2*)(Eout + (size_t)bm * DD))[lane] = make_float2(rx, ry);
        nx += e * rx; ny += e * ry; den += e;
    }

    sx[w][lane] = nx; sy[w][lane] = ny;
    if (lane == 0) sd[w] = den;
    __syncthreads();
    if (w == 0) {
        const float ox = sx[0][lane] + sx[1][lane] + sx[2][lane] + sx[3][lane];
        const float oy = sy[0][lane] + sy[1][lane] + sy[2][lane] + sy[3][lane];
        float* prow = pout + ((size_t)b * NCHUNK + c) * PSTRIDE;
        ((float2*)prow)[lane] = make_float2(ox, oy);
        if (lane == 0) prow[DD] = sd[0] + sd[1] + sd[2] + sd[3];
    }
}

// ====================== PRIMARY PATH (5 kernels, cvt folded into hops) ======================

// cvt tables 0,1 only (what hop0 needs). 4000 blocks x 256, 1 unit/thread.
__global__ __launch_bounds__(256) void cvt01(const float* __restrict__ C,
                                             unsigned* __restrict__ Cb) {
    const size_t g = (size_t)blockIdx.x * 256 + threadIdx.x;
    if (g < 2 * UTAB) cvt_unit(C, Cb, g);
}

// hop kernel with optional cvt tail: converts cvt_units units at cvt_base (grid-strided).
template <int HOP, int CVT>
__global__ __launch_bounds__(256) void hop_k(const int* __restrict__ story,
                                             const unsigned* __restrict__ Clog,
                                             const unsigned* __restrict__ Cout,
                                             const float* __restrict__ Elog,
                                             float* __restrict__ Eout,
                                             const float* __restrict__ uprev,
                                             const float* __restrict__ pin,
                                             float* __restrict__ uwrite,
                                             float* __restrict__ logit,
                                             float* __restrict__ pout,
                                             const float* __restrict__ Cmat,
                                             unsigned* __restrict__ Cb,
                                             size_t cvt_base) {
    __shared__ float su[DD];
    __shared__ float sx[4][64], sy[4][64];
    __shared__ float sd[4];
    hop_body<HOP>(blockIdx.y, blockIdx.x, threadIdx.x, story, Clog, Cout, Elog,
                  Eout, uprev, pin, uwrite, logit, pout, su, sx, sy, sd);
    if (CVT) {
        // 2048 blocks x 256 threads = 524288 >= UTAB; each thread converts <=1 unit
        const size_t blk = (size_t)blockIdx.y * gridDim.x + blockIdx.x;
        const size_t g = blk * 256 + threadIdx.x;
        if (g < UTAB) cvt_unit(Cmat, Cb, cvt_base + g);
    }
}

// final: uout = u2 + red(P2)
__global__ __launch_bounds__(128) void final_u(const float* __restrict__ pin,
                                               const float* __restrict__ u2,
                                               float* __restrict__ uout) {
    const int b = blockIdx.x, d = threadIdx.x;
    float num = 0.f, den = 0.f;
    for (int cc = 0; cc < NCHUNK; ++cc) {
        const float* p = pin + ((size_t)b * NCHUNK + cc) * PSTRIDE;
        num += p[d];
        den += p[DD];
    }
    uout[b * DD + d] = u2[b * DD + d] + num / den;
}

// ====================== FALLBACK PATH (round-1, known-good) ======================
__global__ __launch_bounds__(256) void init_u(const float* __restrict__ hidden,
                                              float* __restrict__ u) {
    int i = blockIdx.x * 256 + threadIdx.x;
    if (i < BB * DD) u[i] = hidden[i];
}

__global__ __launch_bounds__(256) void logit_kernel(const int* __restrict__ story,
                                                    const float* __restrict__ Ch,
                                                    const float* __restrict__ u,
                                                    float* __restrict__ logit) {
    int wid = (blockIdx.x * 256 + threadIdx.x) >> 6;
    int lane = threadIdx.x & 63;
    if (wid >= BB * MM) return;
    int b = wid >> 9;
    const int* st = story + (size_t)wid * SS;
    int tok[SS];
#pragma unroll
    for (int s = 0; s < SS; ++s) tok[s] = st[s];
    float ax = 0.f, ay = 0.f;
#pragma unroll
    for (int s = 0; s < SS; ++s) {
        const float2 v = ((const float2*)(Ch + (size_t)tok[s] * DD))[lane];
        ax += v.x; ay += v.y;
    }
    const float2 uv = ((const float2*)(u + b * DD))[lane];
    float p = ax * uv.x + ay * uv.y;
#pragma unroll
    for (int off = 32; off; off >>= 1) p += __shfl_down(p, off, 64);
    if (lane == 0) logit[wid] = p;
}

__global__ __launch_bounds__(256) void softmax_kernel(const float* __restrict__ logit,
                                                      float* __restrict__ prob) {
    int b = blockIdx.x;
    int t = threadIdx.x;
    __shared__ float red[8];
    float l0 = logit[b * MM + t];
    float l1 = logit[b * MM + 256 + t];
    float mx = fmaxf(l0, l1);
#pragma unroll
    for (int off = 32; off; off >>= 1) mx = fmaxf(mx, __shfl_xor(mx, off, 64));
    if ((t & 63) == 0) red[t >> 6] = mx;
    __syncthreads();
    mx = fmaxf(fmaxf(red[0], red[1]), fmaxf(red[2], red[3]));
    float e0 = expf(l0 - mx), e1 = expf(l1 - mx);
    float s = e0 + e1;
#pragma unroll
    for (int off = 32; off; off >>= 1) s += __shfl_xor(s, off, 64);
    if ((t & 63) == 0) red[4 + (t >> 6)] = s;
    __syncthreads();
    s = red[4] + red[5] + red[6] + red[7];
    float inv = 1.0f / s;
    prob[b * MM + t] = e0 * inv;
    prob[b * MM + 256 + t] = e1 * inv;
}

__global__ __launch_bounds__(256) void partial_kernel(const int* __restrict__ story,
                                                      const float* __restrict__ Ch1,
                                                      const float* __restrict__ prob,
                                                      float* __restrict__ partial,
                                                      int chunk) {
    int b = blockIdx.y, c = blockIdx.x;
    int w = threadIdx.x >> 6, lane = threadIdx.x & 63;
    int m0 = c * chunk;
    float ax = 0.f, ay = 0.f;
    for (int m = m0 + w; m < m0 + chunk; m += 4) {
        float pw = prob[b * MM + m];
        const int* st = story + (size_t)(b * MM + m) * SS;
        int tok[SS];
#pragma unroll
        for (int s = 0; s < SS; ++s) tok[s] = st[s];
        float sx = 0.f, sy = 0.f;
#pragma unroll
        for (int s = 0; s < SS; ++s) {
            const float2 v = ((const float2*)(Ch1 + (size_t)tok[s] * DD))[lane];
            sx += v.x; sy += v.y;
        }
        ax += pw * sx; ay += pw * sy;
    }
    __shared__ float redx[4][64];
    __shared__ float redy[4][64];
    redx[w][lane] = ax;
    redy[w][lane] = ay;
    __syncthreads();
    if (w == 0) {
        float ox = redx[0][lane] + redx[1][lane] + redx[2][lane] + redx[3][lane];
        float oy = redy[0][lane] + redy[1][lane] + redy[2][lane] + redy[3][lane];
        float2* dst = (float2*)(partial + ((size_t)b * gridDim.x + c) * DD);
        dst[lane] = make_float2(ox, oy);
    }
}

__global__ __launch_bounds__(256) void update_kernel(const float* __restrict__ partial,
                                                     float* __restrict__ u, int NC) {
    int i = blockIdx.x * 256 + threadIdx.x;
    if (i >= BB * DD) return;
    int b = i >> 7, d = i & 127;
    float s = 0.f;
    for (int c = 0; c < NC; ++c) s += partial[((size_t)b * NC + c) * DD + d];
    u[i] += s;
}

extern "C" void kernel_launch(void* const* d_in, const int* in_sizes, int n_in,
                              void* d_out, int out_size, void* d_ws, size_t ws_size,
                              hipStream_t stream) {
    const int*   story  = (const int*)d_in[0];
    const float* hidden = (const float*)d_in[1];
    const float* Cmat   = (const float*)d_in[2];

    float* out   = (float*)d_out;
    float* logit = out;              // final prob_logit [B,M]
    float* uout  = out + BB * MM;    // final u [B,D]

    // ws layout (float words): Cb (bf16 pairs) | E1 | E2 | Pa | Pb | u1 u2
    const size_t szCb = (size_t)4 * VV * DD / 2;
    const size_t szE  = (size_t)BM * DD;
    const size_t szP  = (size_t)BB * NCHUNK * PSTRIDE;
    const size_t need = (szCb + 2 * szE + 2 * szP + 2 * BB * DD) * sizeof(float);

    if (ws_size >= need) {
        unsigned* Cb = (unsigned*)d_ws;
        float* E1 = (float*)d_ws + szCb;
        float* E2 = E1 + szE;
        float* Pa = E2 + szE;
        float* Pb = Pa + szP;
        float* u1 = Pb + szP;
        float* u2 = u1 + BB * DD;

        const unsigned* C0b = Cb;
        const unsigned* C1b = Cb + (size_t)1 * VV * DD / 2;
        const unsigned* C2b = Cb + (size_t)2 * VV * DD / 2;
        const unsigned* C3b = Cb + (size_t)3 * VV * DD / 2;

        cvt01<<<(unsigned)((2 * UTAB + 255) / 256), 256, 0, stream>>>(Cmat, Cb);
        // hop0 (+ cvt table 2)
        hop_k<0, 1><<<dim3(NCHUNK, BB), 256, 0, stream>>>(
            story, C0b, C1b, nullptr, E1, hidden, nullptr, nullptr, nullptr, Pa,
            Cmat, Cb, 2 * UTAB);
        // hop1 (+ cvt table 3)
        hop_k<1, 1><<<dim3(NCHUNK, BB), 256, 0, stream>>>(
            story, nullptr, C2b, E1, E2, hidden, Pa, u1, nullptr, Pb,
            Cmat, Cb, 3 * UTAB);
        // hop2
        hop_k<2, 0><<<dim3(NCHUNK, BB), 256, 0, stream>>>(
            story, nullptr, C3b, E2, nullptr, u1, Pb, u2, logit, Pa,
            nullptr, nullptr, 0);
        final_u<<<BB, 128, 0, stream>>>(Pa, u2, uout);
    } else {
        float* prob = (float*)d_ws;
        int NC = 32;
        while (NC > 1 && (size_t)(BB * MM + BB * NC * DD) * 4 > ws_size) NC >>= 1;
        float* partial = prob + BB * MM;
        int chunk = MM / NC;

        init_u<<<(BB * DD + 255) / 256, 256, 0, stream>>>(hidden, uout);
        for (int h = 0; h < HOPS; ++h) {
            const float* Ca = Cmat + (size_t)h * VV * DD;
            const float* Cc = Cmat + (size_t)(h + 1) * VV * DD;
            logit_kernel<<<(BB * MM) / 4, 256, 0, stream>>>(story, Ca, uout, logit);
            softmax_kernel<<<BB, 256, 0, stream>>>(logit, prob);
            partial_kernel<<<dim3(NC, BB), 256, 0, stream>>>(story, Cc, prob, partial, chunk);
            update_kernel<<<(BB * DD + 255) / 256, 256, 0, stream>>>(partial, uout, NC);
        }
    }
}

// Round 11
// 65.117 us; speedup vs baseline: 3.8377x; 1.0158x over previous
//
#include <hip/hip_runtime.h>

#define BB 32
#define MM 512
#define SS 10
#define VV 32000
#define DD 128
#define HOPS 3
#define BM (BB * MM)
#define NCHUNK 32          // chunks per b -> grid 32*32 = 1024 blocks per hop
#define CHM (MM / NCHUNK)  // 16 m per chunk -> 4 m per wave
#define PSTRIDE 132        // partial row: 128 num + 1 den + pad
#define PAIR_UNITS ((size_t)VV * 32)   // uint4 units per interleaved table-pair

// bf16 helpers (RN pack; exact unpack)
__device__ __forceinline__ unsigned bfrn(float f) {
    unsigned u = __float_as_uint(f);
    return (u + 0x7FFFu + ((u >> 16) & 1u)) >> 16;
}
__device__ __forceinline__ unsigned pk(float a, float b) { return bfrn(a) | (bfrn(b) << 16); }
__device__ __forceinline__ float bflo(unsigned q) { return __uint_as_float(q << 16); }
__device__ __forceinline__ float bfhi(unsigned q) { return __uint_as_float(q & 0xFFFF0000u); }

// Interleaved pair layout: row v = 128 words; word(lane l, table t) = v*128 + 2*l + t.
// uint4 unit j of row v covers lanes 2j,2j+1 -> floats d=4j..4j+3 of both tables.
__device__ __forceinline__ void cvt_pair_unit(const float* __restrict__ CA,
                                              const float* __restrict__ CB,
                                              unsigned* __restrict__ dst, size_t g) {
    const size_t v = g >> 5, j = g & 31;
    const float4 a = ((const float4*)CA)[v * 32 + j];
    const float4 b = ((const float4*)CB)[v * 32 + j];
    uint4 o;
    o.x = pk(a.x, a.y);
    o.y = pk(b.x, b.y);
    o.z = pk(a.z, a.w);
    o.w = pk(b.z, b.w);
    ((uint4*)dst)[v * 32 + j] = o;
}

// ====================== PRIMARY PATH ======================

// K0: build Cb01 (tables 0,1 interleaved). 4000 blocks x 256, 1 unit/thread.
__global__ __launch_bounds__(256) void cvt01(const float* __restrict__ Cmat,
                                             unsigned* __restrict__ Cb01) {
    const size_t g = (size_t)blockIdx.x * 256 + threadIdx.x;
    if (g < PAIR_UNITS)
        cvt_pair_unit(Cmat, Cmat + (size_t)VV * DD, Cb01, g);
}

// shared u-staging: su = uprev (+ P rebuild for pin!=null); c==0 materializes to uwrite
__device__ __forceinline__ void stage_u(const int b, const int c, const int tid,
                                        const float* __restrict__ uprev,
                                        const float* __restrict__ pin,
                                        float* __restrict__ uwrite,
                                        float* __restrict__ su) {
    if (tid < DD) {
        float v = uprev[b * DD + tid];
        if (pin) {
            float num = 0.f, dsum = 0.f;
            for (int cc = 0; cc < NCHUNK; ++cc) {
                const float* p = pin + ((size_t)b * NCHUNK + cc) * PSTRIDE;
                num += p[tid];
                dsum += p[DD];
            }
            v += num / dsum;
            if (c == 0 && uwrite) uwrite[b * DD + tid] = v;
        }
        su[tid] = v;
    }
    __syncthreads();
}

__device__ __forceinline__ void write_partial(const int b, const int c,
                                              const int w, const int lane,
                                              float nx, float ny, float den,
                                              float* __restrict__ pout,
                                              float (*sx)[64], float (*sy)[64],
                                              float* sd) {
    sx[w][lane] = nx; sy[w][lane] = ny;
    if (lane == 0) sd[w] = den;
    __syncthreads();
    if (w == 0) {
        const float ox = sx[0][lane] + sx[1][lane] + sx[2][lane] + sx[3][lane];
        const float oy = sy[0][lane] + sy[1][lane] + sy[2][lane] + sy[3][lane];
        float* prow = pout + ((size_t)b * NCHUNK + c) * PSTRIDE;
        ((float2*)prow)[lane] = make_float2(ox, oy);
        if (lane == 0) prow[DD] = sd[0] + sd[1] + sd[2] + sd[3];
    }
}

// HOP0: one dwordx2 gather/token from Cb01 -> logit (C0 half) + E1/output (C1 half).
// Tail: this block's share of cvt(C2,C3) -> Cb23.
__global__ __launch_bounds__(256) void hop0_k(const int* __restrict__ story,
                                              const unsigned* __restrict__ Cb01,
                                              float* __restrict__ E1,
                                              const float* __restrict__ hidden,
                                              float* __restrict__ pout,
                                              const float* __restrict__ Cmat,
                                              unsigned* __restrict__ Cb23) {
    const int b = blockIdx.y, c = blockIdx.x;
    const int tid = threadIdx.x;
    const int w = tid >> 6, lane = tid & 63;
    __shared__ float su[DD];
    __shared__ float sx[4][64], sy[4][64];
    __shared__ float sd[4];

    stage_u(b, c, tid, hidden, nullptr, nullptr, su);
    const float2 uv = ((const float2*)su)[lane];
    const uint2* G = (const uint2*)Cb01;

    float nx = 0.f, ny = 0.f, den = 0.f;
#pragma unroll
    for (int k = 0; k < CHM / 4; ++k) {
        const int m = c * CHM + k * 4 + w;
        const int bm = b * MM + m;
        int tok[SS];
        const int* st = story + (size_t)bm * SS;
#pragma unroll
        for (int s = 0; s < SS; ++s) tok[s] = st[s];

        float ex = 0.f, ey = 0.f, rx = 0.f, ry = 0.f;
#pragma unroll
        for (int s = 0; s < SS; ++s) {
            const uint2 q = G[(size_t)tok[s] * 64 + lane];
            ex += bflo(q.x); ey += bfhi(q.x);
            rx += bflo(q.y); ry += bfhi(q.y);
        }
        float l = ex * uv.x + ey * uv.y;
#pragma unroll
        for (int off = 32; off; off >>= 1) l += __shfl_xor(l, off, 64);
        const float e = expf(l);

        ((float2*)(E1 + (size_t)bm * DD))[lane] = make_float2(rx, ry);
        nx += e * rx; ny += e * ry; den += e;
    }
    write_partial(b, c, w, lane, nx, ny, den, pout, sx, sy, sd);

    // cvt tail: tables 2,3 -> Cb23. 1024 blocks x 256 thr x 4 units >= PAIR_UNITS.
    const size_t t0 = (((size_t)blockIdx.y * gridDim.x + blockIdx.x) * 256 + tid) * 4;
#pragma unroll
    for (int i = 0; i < 4; ++i) {
        const size_t g = t0 + i;
        if (g < PAIR_UNITS)
            cvt_pair_unit(Cmat + (size_t)2 * VV * DD, Cmat + (size_t)3 * VV * DD,
                          Cb23, g);
    }
}

// HOP1: logit from E1 (dense); one dwordx2 gather/token from Cb23 -> E2 (C2, also
// this hop's output) and E3 (C3, hop2's output). u rebuilt from hidden+P0.
__global__ __launch_bounds__(256) void hop1_k(const int* __restrict__ story,
                                              const unsigned* __restrict__ Cb23,
                                              const float* __restrict__ E1,
                                              float* __restrict__ E2,
                                              float* __restrict__ E3,
                                              const float* __restrict__ hidden,
                                              const float* __restrict__ pin,
                                              float* __restrict__ u1,
                                              float* __restrict__ pout) {
    const int b = blockIdx.y, c = blockIdx.x;
    const int tid = threadIdx.x;
    const int w = tid >> 6, lane = tid & 63;
    __shared__ float su[DD];
    __shared__ float sx[4][64], sy[4][64];
    __shared__ float sd[4];

    stage_u(b, c, tid, hidden, pin, u1, su);
    const float2 uv = ((const float2*)su)[lane];
    const uint2* G = (const uint2*)Cb23;

    float nx = 0.f, ny = 0.f, den = 0.f;
#pragma unroll
    for (int k = 0; k < CHM / 4; ++k) {
        const int m = c * CHM + k * 4 + w;
        const int bm = b * MM + m;
        int tok[SS];
        const int* st = story + (size_t)bm * SS;
#pragma unroll
        for (int s = 0; s < SS; ++s) tok[s] = st[s];

        const float2 ev = ((const float2*)(E1 + (size_t)bm * DD))[lane];
        float l = ev.x * uv.x + ev.y * uv.y;
#pragma unroll
        for (int off = 32; off; off >>= 1) l += __shfl_xor(l, off, 64);
        const float e = expf(l);

        float r2x = 0.f, r2y = 0.f, r3x = 0.f, r3y = 0.f;
#pragma unroll
        for (int s = 0; s < SS; ++s) {
            const uint2 q = G[(size_t)tok[s] * 64 + lane];
            r2x += bflo(q.x); r2y += bfhi(q.x);
            r3x += bflo(q.y); r3y += bfhi(q.y);
        }
        ((float2*)(E2 + (size_t)bm * DD))[lane] = make_float2(r2x, r2y);
        ((float2*)(E3 + (size_t)bm * DD))[lane] = make_float2(r3x, r3y);
        nx += e * r2x; ny += e * r2y; den += e;
    }
    write_partial(b, c, w, lane, nx, ny, den, pout, sx, sy, sd);
}

// HOP2: fully dense — logit from E2 (writes final logit), output from E3.
__global__ __launch_bounds__(256) void hop2_k(const float* __restrict__ E2,
                                              const float* __restrict__ E3,
                                              const float* __restrict__ u1,
                                              const float* __restrict__ pin,
                                              float* __restrict__ u2,
                                              float* __restrict__ logit,
                                              float* __restrict__ pout) {
    const int b = blockIdx.y, c = blockIdx.x;
    const int tid = threadIdx.x;
    const int w = tid >> 6, lane = tid & 63;
    __shared__ float su[DD];
    __shared__ float sx[4][64], sy[4][64];
    __shared__ float sd[4];

    stage_u(b, c, tid, u1, pin, u2, su);
    const float2 uv = ((const float2*)su)[lane];

    float nx = 0.f, ny = 0.f, den = 0.f;
#pragma unroll
    for (int k = 0; k < CHM / 4; ++k) {
        const int m = c * CHM + k * 4 + w;
        const int bm = b * MM + m;

        const float2 ev = ((const float2*)(E2 + (size_t)bm * DD))[lane];
        float l = ev.x * uv.x + ev.y * uv.y;
#pragma unroll
        for (int off = 32; off; off >>= 1) l += __shfl_xor(l, off, 64);
        if (lane == 0) logit[bm] = l;
        const float e = expf(l);

        const float2 rv = ((const float2*)(E3 + (size_t)bm * DD))[lane];
        nx += e * rv.x; ny += e * rv.y; den += e;
    }
    write_partial(b, c, w, lane, nx, ny, den, pout, sx, sy, sd);
}

// final: uout = u2 + red(P2)
__global__ __launch_bounds__(128) void final_u(const float* __restrict__ pin,
                                               const float* __restrict__ u2,
                                               float* __restrict__ uout) {
    const int b = blockIdx.x, d = threadIdx.x;
    float num = 0.f, den = 0.f;
    for (int cc = 0; cc < NCHUNK; ++cc) {
        const float* p = pin + ((size_t)b * NCHUNK + cc) * PSTRIDE;
        num += p[d];
        den += p[DD];
    }
    uout[b * DD + d] = u2[b * DD + d] + num / den;
}

// ====================== FALLBACK PATH (round-1, known-good) ======================
__global__ __launch_bounds__(256) void init_u(const float* __restrict__ hidden,
                                              float* __restrict__ u) {
    int i = blockIdx.x * 256 + threadIdx.x;
    if (i < BB * DD) u[i] = hidden[i];
}

__global__ __launch_bounds__(256) void logit_kernel(const int* __restrict__ story,
                                                    const float* __restrict__ Ch,
                                                    const float* __restrict__ u,
                                                    float* __restrict__ logit) {
    int wid = (blockIdx.x * 256 + threadIdx.x) >> 6;
    int lane = threadIdx.x & 63;
    if (wid >= BB * MM) return;
    int b = wid >> 9;
    const int* st = story + (size_t)wid * SS;
    int tok[SS];
#pragma unroll
    for (int s = 0; s < SS; ++s) tok[s] = st[s];
    float ax = 0.f, ay = 0.f;
#pragma unroll
    for (int s = 0; s < SS; ++s) {
        const float2 v = ((const float2*)(Ch + (size_t)tok[s] * DD))[lane];
        ax += v.x; ay += v.y;
    }
    const float2 uv = ((const float2*)(u + b * DD))[lane];
    float p = ax * uv.x + ay * uv.y;
#pragma unroll
    for (int off = 32; off; off >>= 1) p += __shfl_down(p, off, 64);
    if (lane == 0) logit[wid] = p;
}

__global__ __launch_bounds__(256) void softmax_kernel(const float* __restrict__ logit,
                                                      float* __restrict__ prob) {
    int b = blockIdx.x;
    int t = threadIdx.x;
    __shared__ float red[8];
    float l0 = logit[b * MM + t];
    float l1 = logit[b * MM + 256 + t];
    float mx = fmaxf(l0, l1);
#pragma unroll
    for (int off = 32; off; off >>= 1) mx = fmaxf(mx, __shfl_xor(mx, off, 64));
    if ((t & 63) == 0) red[t >> 6] = mx;
    __syncthreads();
    mx = fmaxf(fmaxf(red[0], red[1]), fmaxf(red[2], red[3]));
    float e0 = expf(l0 - mx), e1 = expf(l1 - mx);
    float s = e0 + e1;
#pragma unroll
    for (int off = 32; off; off >>= 1) s += __shfl_xor(s, off, 64);
    if ((t & 63) == 0) red[4 + (t >> 6)] = s;
    __syncthreads();
    s = red[4] + red[5] + red[6] + red[7];
    float inv = 1.0f / s;
    prob[b * MM + t] = e0 * inv;
    prob[b * MM + 256 + t] = e1 * inv;
}

__global__ __launch_bounds__(256) void partial_kernel(const int* __restrict__ story,
                                                      const float* __restrict__ Ch1,
                                                      const float* __restrict__ prob,
                                                      float* __restrict__ partial,
                                                      int chunk) {
    int b = blockIdx.y, c = blockIdx.x;
    int w = threadIdx.x >> 6, lane = threadIdx.x & 63;
    int m0 = c * chunk;
    float ax = 0.f, ay = 0.f;
    for (int m = m0 + w; m < m0 + chunk; m += 4) {
        float pw = prob[b * MM + m];
        const int* st = story + (size_t)(b * MM + m) * SS;
        int tok[SS];
#pragma unroll
        for (int s = 0; s < SS; ++s) tok[s] = st[s];
        float sx = 0.f, sy = 0.f;
#pragma unroll
        for (int s = 0; s < SS; ++s) {
            const float2 v = ((const float2*)(Ch1 + (size_t)tok[s] * DD))[lane];
            sx += v.x; sy += v.y;
        }
        ax += pw * sx; ay += pw * sy;
    }
    __shared__ float redx[4][64];
    __shared__ float redy[4][64];
    redx[w][lane] = ax;
    redy[w][lane] = ay;
    __syncthreads();
    if (w == 0) {
        float ox = redx[0][lane] + redx[1][lane] + redx[2][lane] + redx[3][lane];
        float oy = redy[0][lane] + redy[1][lane] + redy[2][lane] + redy[3][lane];
        float2* dst = (float2*)(partial + ((size_t)b * gridDim.x + c) * DD);
        dst[lane] = make_float2(ox, oy);
    }
}

__global__ __launch_bounds__(256) void update_kernel(const float* __restrict__ partial,
                                                     float* __restrict__ u, int NC) {
    int i = blockIdx.x * 256 + threadIdx.x;
    if (i >= BB * DD) return;
    int b = i >> 7, d = i & 127;
    float s = 0.f;
    for (int c = 0; c < NC; ++c) s += partial[((size_t)b * NC + c) * DD + d];
    u[i] += s;
}

extern "C" void kernel_launch(void* const* d_in, const int* in_sizes, int n_in,
                              void* d_out, int out_size, void* d_ws, size_t ws_size,
                              hipStream_t stream) {
    const int*   story  = (const int*)d_in[0];
    const float* hidden = (const float*)d_in[1];
    const float* Cmat   = (const float*)d_in[2];

    float* out   = (float*)d_out;
    float* logit = out;              // final prob_logit [B,M]
    float* uout  = out + BB * MM;    // final u [B,D]

    // ws words: Cb01 | Cb23 | E1 E2 E3 | Pa Pb | u1 u2
    const size_t szCbp = (size_t)VV * 128;              // words per interleaved pair
    const size_t szE   = (size_t)BM * DD;
    const size_t szP   = (size_t)BB * NCHUNK * PSTRIDE;
    const size_t need  = (2 * szCbp + 3 * szE + 2 * szP + 2 * BB * DD) * sizeof(float);

    if (ws_size >= need) {
        unsigned* Cb01 = (unsigned*)d_ws;
        unsigned* Cb23 = Cb01 + szCbp;
        float* E1 = (float*)d_ws + 2 * szCbp;
        float* E2 = E1 + szE;
        float* E3 = E2 + szE;
        float* Pa = E3 + szE;
        float* Pb = Pa + szP;
        float* u1 = Pb + szP;
        float* u2 = u1 + BB * DD;

        cvt01<<<(unsigned)((PAIR_UNITS + 255) / 256), 256, 0, stream>>>(Cmat, Cb01);
        hop0_k<<<dim3(NCHUNK, BB), 256, 0, stream>>>(story, Cb01, E1, hidden, Pa,
                                                     Cmat, Cb23);
        hop1_k<<<dim3(NCHUNK, BB), 256, 0, stream>>>(story, Cb23, E1, E2, E3,
                                                     hidden, Pa, u1, Pb);
        hop2_k<<<dim3(NCHUNK, BB), 256, 0, stream>>>(E2, E3, u1, Pb, u2, logit, Pa);
        final_u<<<BB, 128, 0, stream>>>(Pa, u2, uout);
    } else {
        float* prob = (float*)d_ws;
        int NC = 32;
        while (NC > 1 && (size_t)(BB * MM + BB * NC * DD) * 4 > ws_size) NC >>= 1;
        float* partial = prob + BB * MM;
        int chunk = MM / NC;

        init_u<<<(BB * DD + 255) / 256, 256, 0, stream>>>(hidden, uout);
        for (int h = 0; h < HOPS; ++h) {
            const float* Ca = Cmat + (size_t)h * VV * DD;
            const float* Cc = Cmat + (size_t)(h + 1) * VV * DD;
            logit_kernel<<<(BB * MM) / 4, 256, 0, stream>>>(story, Ca, uout, logit);
            softmax_kernel<<<BB, 256, 0, stream>>>(logit, prob);
            partial_kernel<<<dim3(NC, BB), 256, 0, stream>>>(story, Cc, prob, partial, chunk);
            update_kernel<<<(BB * DD + 255) / 256, 256, 0, stream>>>(partial, uout, NC);
        }
    }
}